// Round 1
// baseline (1335.526 us; speedup 1.0000x reference)
//
#include <hip/hip_runtime.h>

typedef unsigned short u16;
typedef unsigned int u32;
typedef __bf16 bf16x8 __attribute__((ext_vector_type(8)));
typedef float f32x4 __attribute__((ext_vector_type(4)));
typedef u16 u16x4 __attribute__((ext_vector_type(4)));
typedef u16 u16x8 __attribute__((ext_vector_type(8)));

#define N_TW 1024
#define L_TOK 64
#define M1 (N_TW * L_TOK)

__device__ __forceinline__ u16 f2bf(float f) {
  u32 u = __builtin_bit_cast(u32, f);
  u += 0x7fffu + ((u >> 16) & 1u);
  return (u16)(u >> 16);
}
__device__ __forceinline__ float bf2f(u16 b) {
  u32 u = ((u32)b) << 16;
  return __builtin_bit_cast(float, u);
}
__device__ __forceinline__ void gl_lds16(const void* g, void* l) {
  __builtin_amdgcn_global_load_lds((const __attribute__((address_space(1))) u32*)g,
                                   (__attribute__((address_space(3))) u32*)l, 16, 0, 0);
}
__device__ __forceinline__ float sigf(float x) { return 1.f / (1.f + __expf(-x)); }
__device__ __forceinline__ float tanh_(float x) { return 1.f - 2.f / (__expf(2.f * x) + 1.f); }

// ---------------- prep: fp32 -> bf16 weight conversion ----------------
__global__ __launch_bounds__(256) void k_f2bf(const float* __restrict__ s, u16* __restrict__ d, int n) {
  int i = (blockIdx.x * 256 + threadIdx.x) * 4;
  if (i < n) {
    float4 v = *(const float4*)(s + i);
    u16x4 o;
    o.x = f2bf(v.x); o.y = f2bf(v.y); o.z = f2bf(v.z); o.w = f2bf(v.w);
    *(u16x4*)(d + i) = o;
  }
}

__global__ __launch_bounds__(256) void k_bias(const float* __restrict__ a, const float* __restrict__ b,
                                              const float* __restrict__ c, const float* __restrict__ d,
                                              float* __restrict__ o) {
  int i = blockIdx.x * 256 + threadIdx.x;  // 0..2047
  o[i] = (i < 1024) ? (a[i] + b[i]) : (c[i - 1024] + d[i - 1024]);
}

// ---------------- embedding gather + bf16 convert ----------------
__global__ __launch_bounds__(256) void k_gather(const int* __restrict__ tok, const float* __restrict__ emb,
                                                u16* __restrict__ x) {
  long long t = (long long)blockIdx.x * 256 + threadIdx.x;  // 4,194,304 threads
  long long base = t * 8;                                   // elem index in [0, 65536*512)
  int row = (int)(base >> 9);
  int col = (int)(base & 511);
  long long src = (long long)tok[row] * 512 + col;
  float4 a = *(const float4*)(emb + src);
  float4 b = *(const float4*)(emb + src + 4);
  u16x8 o;
  o[0] = f2bf(a.x); o[1] = f2bf(a.y); o[2] = f2bf(a.z); o[3] = f2bf(a.w);
  o[4] = f2bf(b.x); o[5] = f2bf(b.y); o[6] = f2bf(b.z); o[7] = f2bf(b.w);
  *(u16x8*)(x + base) = o;
}

// ---------------- GEMM: xg[65536,2048] = X[65536,512] @ W[2048,512]^T + bias ----------------
// 128x128 tile, BK=32, 4 waves (each wave: 32 rows x 128 cols = 2x8 MFMA frags)
__global__ __launch_bounds__(256) void k_gemm_xg(const u16* __restrict__ X, const u16* __restrict__ W,
                                                 const float* __restrict__ bias, u16* __restrict__ XG) {
  __shared__ u16 Al[128 * 32];
  __shared__ u16 Bl[128 * 32];
  const int tid = threadIdx.x;
  const int wv = tid >> 6, lane = tid & 63;
  const int bm = blockIdx.x, bn = blockIdx.y;
  f32x4 acc[2][8] = {};
  const int lr = lane & 15, lk = (lane >> 4) * 8;
  for (int kt = 0; kt < 16; ++kt) {
    for (int i = 0; i < 2; ++i) {
      int lin = (wv * 2 + i) * 64 + lane;
      int r = lin >> 2, kc = lin & 3;
      int k = kt * 32 + kc * 8;
      gl_lds16(X + (long long)(bm * 128 + r) * 512 + k, &Al[(wv * 2 + i) * 512]);
      gl_lds16(W + (long long)(bn * 128 + r) * 512 + k, &Bl[(wv * 2 + i) * 512]);
    }
    __syncthreads();
    bf16x8 a0 = *(const bf16x8*)&Al[(wv * 32 + lr) * 32 + lk];
    bf16x8 a1 = *(const bf16x8*)&Al[(wv * 32 + 16 + lr) * 32 + lk];
    for (int nj = 0; nj < 8; ++nj) {
      bf16x8 b = *(const bf16x8*)&Bl[(nj * 16 + lr) * 32 + lk];
      acc[0][nj] = __builtin_amdgcn_mfma_f32_16x16x32_bf16(a0, b, acc[0][nj], 0, 0, 0);
      acc[1][nj] = __builtin_amdgcn_mfma_f32_16x16x32_bf16(a1, b, acc[1][nj], 0, 0, 0);
    }
    __syncthreads();
  }
  const int lh = lane >> 4;
  for (int mi = 0; mi < 2; ++mi)
    for (int nj = 0; nj < 8; ++nj) {
      int col = bn * 128 + nj * 16 + lr;
      float bv = bias[col];
      for (int r = 0; r < 4; ++r) {
        int row = bm * 128 + wv * 32 + mi * 16 + lh * 4 + r;
        XG[(long long)row * 2048 + col] = f2bf(acc[mi][nj][r] + bv);
      }
    }
}

// ---------------- image mean over 49 positions ----------------
__global__ __launch_bounds__(256) void k_imgmean(const float* __restrict__ img, u16* __restrict__ o) {
  int n = blockIdx.x;
  for (int j = 0; j < 2; ++j) {
    int col = threadIdx.x + j * 256;
    const float* p = img + (long long)n * 49 * 512 + col;
    float s = 0.f;
    for (int r = 0; r < 49; ++r) s += p[r * 512];
    o[(long long)n * 512 + col] = f2bf(s * (1.f / 49.f));
  }
}

// ---------------- image GEMM: O[1024,512] = A[1024,512] @ Wimg[512,512]^T + bias (fp32 out) ----------------
__global__ __launch_bounds__(256) void k_gemm_img(const u16* __restrict__ A, const u16* __restrict__ W,
                                                  const float* __restrict__ bias, float* __restrict__ O) {
  __shared__ u16 Al[128 * 32];
  __shared__ u16 Bl[128 * 32];
  const int tid = threadIdx.x;
  const int wv = tid >> 6, lane = tid & 63;
  const int bm = blockIdx.x, bn = blockIdx.y;  // 8 x 4
  f32x4 acc[2][8] = {};
  const int lr = lane & 15, lk = (lane >> 4) * 8;
  for (int kt = 0; kt < 16; ++kt) {
    for (int i = 0; i < 2; ++i) {
      int lin = (wv * 2 + i) * 64 + lane;
      int r = lin >> 2, kc = lin & 3;
      int k = kt * 32 + kc * 8;
      gl_lds16(A + (long long)(bm * 128 + r) * 512 + k, &Al[(wv * 2 + i) * 512]);
      gl_lds16(W + (long long)(bn * 128 + r) * 512 + k, &Bl[(wv * 2 + i) * 512]);
    }
    __syncthreads();
    bf16x8 a0 = *(const bf16x8*)&Al[(wv * 32 + lr) * 32 + lk];
    bf16x8 a1 = *(const bf16x8*)&Al[(wv * 32 + 16 + lr) * 32 + lk];
    for (int nj = 0; nj < 8; ++nj) {
      bf16x8 b = *(const bf16x8*)&Bl[(nj * 16 + lr) * 32 + lk];
      acc[0][nj] = __builtin_amdgcn_mfma_f32_16x16x32_bf16(a0, b, acc[0][nj], 0, 0, 0);
      acc[1][nj] = __builtin_amdgcn_mfma_f32_16x16x32_bf16(a1, b, acc[1][nj], 0, 0, 0);
    }
    __syncthreads();
  }
  const int lh = lane >> 4;
  for (int mi = 0; mi < 2; ++mi)
    for (int nj = 0; nj < 8; ++nj) {
      int col = bn * 128 + nj * 16 + lr;
      float bv = bias[col];
      for (int r = 0; r < 4; ++r) {
        int row = bm * 128 + wv * 32 + mi * 16 + lh * 4 + r;
        O[(long long)row * 512 + col] = acc[mi][nj][r] + bv;
      }
    }
}

// ---------------- LSTM step: g = Hin @ Whh^T (gate-permuted cols) + xg_t, then cell ----------------
// grid (16, 8): bm over 2048 "tweets" (0..1023 fwd, 1024..2047 bwd), bn over 8 h-slices of 32.
// B cols permuted: col c in [0,128) -> gate (c>>5), h index bn*32 + (c&31). So each block owns
// i,f,g,o for its h-slice and the cell update is lane-local in the MFMA C layout.
__global__ __launch_bounds__(256) void k_lstm(const u16* __restrict__ Hin, u16* __restrict__ Hout,
                                              const u16* __restrict__ Whh, const u16* __restrict__ XG,
                                              float* __restrict__ C, float* __restrict__ Hf, int t) {
  __shared__ u16 Al[128 * 32];
  __shared__ u16 Bl[128 * 32];
  const int tid = threadIdx.x;
  const int wv = tid >> 6, lane = tid & 63;
  const int bm = blockIdx.x, bn = blockIdx.y;
  const int dir = bm >> 3;
  f32x4 acc[2][8] = {};
  const int lr = lane & 15, lk = (lane >> 4) * 8;
  for (int kt = 0; kt < 8; ++kt) {
    for (int i = 0; i < 2; ++i) {
      int lin = (wv * 2 + i) * 64 + lane;
      int r = lin >> 2, kc = lin & 3;
      int k = kt * 32 + kc * 8;
      gl_lds16(Hin + (long long)(bm * 128 + r) * 256 + k, &Al[(wv * 2 + i) * 512]);
      int gate = r >> 5;
      int hj = bn * 32 + (r & 31);
      gl_lds16(Whh + (long long)dir * 262144 + (long long)(gate * 256 + hj) * 256 + k,
               &Bl[(wv * 2 + i) * 512]);
    }
    __syncthreads();
    bf16x8 a0 = *(const bf16x8*)&Al[(wv * 32 + lr) * 32 + lk];
    bf16x8 a1 = *(const bf16x8*)&Al[(wv * 32 + 16 + lr) * 32 + lk];
    for (int nj = 0; nj < 8; ++nj) {
      bf16x8 b = *(const bf16x8*)&Bl[(nj * 16 + lr) * 32 + lk];
      acc[0][nj] = __builtin_amdgcn_mfma_f32_16x16x32_bf16(a0, b, acc[0][nj], 0, 0, 0);
      acc[1][nj] = __builtin_amdgcn_mfma_f32_16x16x32_bf16(a1, b, acc[1][nj], 0, 0, 0);
    }
    __syncthreads();
  }
  const int lh = lane >> 4;
  const int lt = dir ? (63 - t) : t;
  for (int mi = 0; mi < 2; ++mi)
    for (int whi = 0; whi < 2; ++whi)
      for (int r = 0; r < 4; ++r) {
        int tw = bm * 128 + wv * 32 + mi * 16 + lh * 4 + r;
        int n = tw & 1023;
        int hj = bn * 32 + whi * 16 + lr;
        long long xb = ((long long)n * 64 + lt) * 2048 + (long long)dir * 1024 + hj;
        float gi = acc[mi][whi][r] + bf2f(XG[xb]);
        float gf = acc[mi][whi + 2][r] + bf2f(XG[xb + 256]);
        float gg = acc[mi][whi + 4][r] + bf2f(XG[xb + 512]);
        float go = acc[mi][whi + 6][r] + bf2f(XG[xb + 768]);
        float iv = sigf(gi), fv = sigf(gf), gv = tanh_(gg), ov = sigf(go);
        long long ci = (long long)tw * 256 + hj;
        float cn = fv * C[ci] + iv * gv;
        C[ci] = cn;
        float hn = ov * tanh_(cn);
        Hout[ci] = f2bf(hn);
        Hf[ci] = hn;
      }
}

// ---------------- attention fusion + mean over tweets (atomic accumulate) ----------------
__global__ __launch_bounds__(256) void k_fusion(const float* __restrict__ Hf, const float* __restrict__ IH,
                                                const float* __restrict__ WT, const float* __restrict__ WI,
                                                float* __restrict__ msum) {
  int wv = threadIdx.x >> 6, lane = threadIdx.x & 63;
  float facc[8] = {0.f, 0.f, 0.f, 0.f, 0.f, 0.f, 0.f, 0.f};
  for (int p = 0; p < 8; ++p) {
    int n = blockIdx.x * 32 + wv * 8 + p;
    float th[8], ih[8];
    float ts = 0.f, is = 0.f;
    for (int j = 0; j < 8; ++j) {
      int e = lane * 8 + j;
      float tv = (e < 256) ? Hf[(long long)n * 256 + e] : Hf[(long long)(1024 + n) * 256 + (e - 256)];
      float iv = IH[(long long)n * 512 + e];
      th[j] = tv; ih[j] = iv;
      ts += tv * WT[e];
      is += iv * WI[e];
    }
    for (int off = 32; off > 0; off >>= 1) {
      ts += __shfl_down(ts, off);
      is += __shfl_down(is, off);
    }
    ts = __shfl(ts, 0);
    is = __shfl(is, 0);
    float a0 = 1.f / (1.f + __expf(is - ts));  // softmax([ts,is])[0]
    float a1 = 1.f - a0;
    for (int j = 0; j < 8; ++j) facc[j] += a0 * th[j] + a1 * ih[j];
  }
  for (int j = 0; j < 8; ++j) atomicAdd(&msum[lane * 8 + j], facc[j]);
}

// ---------------- classifier MLP (single block) ----------------
__global__ __launch_bounds__(256) void k_cls(const float* __restrict__ msum, const float* __restrict__ Wc1,
                                             const float* __restrict__ bc1, const float* __restrict__ Wc2,
                                             const float* __restrict__ bc2, float* __restrict__ out) {
  __shared__ float mf[512];
  __shared__ float hdd[512];
  __shared__ float red[2][256];
  int tid = threadIdx.x;
  for (int j = tid; j < 512; j += 256) mf[j] = msum[j] * (1.f / 1024.f);
  __syncthreads();
  for (int j = tid; j < 512; j += 256) {
    const float* wr = Wc1 + (long long)j * 512;
    float s = bc1[j];
    for (int k = 0; k < 512; ++k) s += mf[k] * wr[k];
    hdd[j] = fmaxf(s, 0.f);
  }
  __syncthreads();
  float s0 = 0.f, s1 = 0.f;
  for (int k = tid; k < 512; k += 256) {
    s0 += hdd[k] * Wc2[k];
    s1 += hdd[k] * Wc2[512 + k];
  }
  red[0][tid] = s0;
  red[1][tid] = s1;
  __syncthreads();
  if (tid < 2) {
    float s = 0.f;
    for (int k = 0; k < 256; ++k) s += red[tid][k];
    out[tid] = s + bc2[tid];
  }
}

extern "C" void kernel_launch(void* const* d_in, const int* in_sizes, int n_in,
                              void* d_out, int out_size, void* d_ws, size_t ws_size,
                              hipStream_t stream) {
  const int* tokens = (const int*)d_in[0];
  const float* images = (const float*)d_in[1];
  const float* embed = (const float*)d_in[2];
  const float* Wih_f = (const float*)d_in[3];
  const float* Whh_f = (const float*)d_in[4];
  const float* bih_f = (const float*)d_in[5];
  const float* bhh_f = (const float*)d_in[6];
  const float* Wih_b = (const float*)d_in[7];
  const float* Whh_b = (const float*)d_in[8];
  const float* bih_b = (const float*)d_in[9];
  const float* bhh_b = (const float*)d_in[10];
  const float* Wimg = (const float*)d_in[11];
  const float* bimg = (const float*)d_in[12];
  const float* W_T = (const float*)d_in[13];
  const float* W_I = (const float*)d_in[14];
  const float* Wc1 = (const float*)d_in[15];
  const float* bc1 = (const float*)d_in[16];
  const float* Wc2 = (const float*)d_in[17];
  const float* bc2 = (const float*)d_in[18];
  float* out = (float*)d_out;

  char* ws = (char*)d_ws;
  size_t off = 0;
  auto alloc = [&](size_t bytes) -> void* {
    void* p = ws + off;
    off += (bytes + 255) & ~(size_t)255;
    return p;
  };
  u16* xbf = (u16*)alloc((size_t)M1 * 512 * 2);         // 64 MiB
  u16* xg = (u16*)alloc((size_t)M1 * 2048 * 2);         // 256 MiB
  u16* wih_bf = (u16*)alloc((size_t)2048 * 512 * 2);
  u16* whh_bf = (u16*)alloc((size_t)2 * 1024 * 256 * 2);
  u16* wimg_bf = (u16*)alloc((size_t)512 * 512 * 2);
  float* bias_a = (float*)alloc((size_t)2048 * 4);
  u16* h0 = (u16*)alloc((size_t)2048 * 256 * 2);
  u16* h1 = (u16*)alloc((size_t)2048 * 256 * 2);
  float* cst = (float*)alloc((size_t)2048 * 256 * 4);
  float* hf32 = (float*)alloc((size_t)2048 * 256 * 4);
  u16* im_bf = (u16*)alloc((size_t)1024 * 512 * 2);
  float* im_h = (float*)alloc((size_t)1024 * 512 * 4);
  float* msum = (float*)alloc((size_t)512 * 4);

  hipMemsetAsync(h0, 0, (size_t)2048 * 256 * 2, stream);
  hipMemsetAsync(cst, 0, (size_t)2048 * 256 * 4, stream);
  hipMemsetAsync(msum, 0, (size_t)512 * 4, stream);

  k_f2bf<<<512, 256, 0, stream>>>(Wih_f, wih_bf, 524288);
  k_f2bf<<<512, 256, 0, stream>>>(Wih_b, wih_bf + 1024 * 512, 524288);
  k_f2bf<<<256, 256, 0, stream>>>(Whh_f, whh_bf, 262144);
  k_f2bf<<<256, 256, 0, stream>>>(Whh_b, whh_bf + 262144, 262144);
  k_f2bf<<<256, 256, 0, stream>>>(Wimg, wimg_bf, 262144);
  k_bias<<<8, 256, 0, stream>>>(bih_f, bhh_f, bih_b, bhh_b, bias_a);

  k_gather<<<16384, 256, 0, stream>>>(tokens, embed, xbf);
  k_gemm_xg<<<dim3(512, 16), 256, 0, stream>>>(xbf, wih_bf, bias_a, xg);

  k_imgmean<<<1024, 256, 0, stream>>>(images, im_bf);
  k_gemm_img<<<dim3(8, 4), 256, 0, stream>>>(im_bf, wimg_bf, bimg, im_h);

  for (int t = 0; t < 64; ++t) {
    const u16* hin = (t & 1) ? h1 : h0;
    u16* hout = (t & 1) ? h0 : h1;
    k_lstm<<<dim3(16, 8), 256, 0, stream>>>(hin, hout, whh_bf, xg, cst, hf32, t);
  }

  k_fusion<<<32, 256, 0, stream>>>(hf32, im_h, W_T, W_I, msum);
  k_cls<<<1, 256, 0, stream>>>(msum, Wc1, bc1, Wc2, bc2, out);
}